// Round 1
// baseline (759.460 us; speedup 1.0000x reference)
//
#include <hip/hip_runtime.h>
#include <math.h>

#define SQRT3F 1.7320508075688772f
#define INV_SQRT3F 0.57735026918962576f

__device__ __forceinline__ float gelu_exact(float x) {
    return 0.5f * x * (1.0f + erff(x * 0.70710678118654752f));
}

// Kernel A: per-edge spherical harmonic accumulation into [N,4] (sumSh.xyz, count)
__global__ __launch_bounds__(256) void edge_kernel(
    const float* __restrict__ pos,
    const int* __restrict__ src,
    const int* __restrict__ dst,
    float* __restrict__ sum4, int E)
{
    int stride = gridDim.x * blockDim.x;
    for (int i = blockIdx.x * blockDim.x + threadIdx.x; i < E; i += stride) {
        int s = src[i], d = dst[i];
        float rx = pos[3*d+0] - pos[3*s+0];
        float ry = pos[3*d+1] - pos[3*s+1];
        float rz = pos[3*d+2] - pos[3*s+2];
        float r = sqrtf(rx*rx + ry*ry + rz*rz);
        float inv = SQRT3F / fmaxf(r, 1e-9f);
        atomicAdd(&sum4[4*d+0], rx*inv);
        atomicAdd(&sum4[4*d+1], ry*inv);
        atomicAdd(&sum4[4*d+2], rz*inv);
        atomicAdd(&sum4[4*d+3], 1.0f);
    }
}

// Kernel B: per-node closed-form 3-layer network, wave-reduced into acc[5]
__global__ __launch_bounds__(256) void node_kernel(
    const float* __restrict__ sum4,
    const float* __restrict__ W0_1, const float* __restrict__ W1_1, const float* __restrict__ b_1,
    const float* __restrict__ Wg1,  const float* __restrict__ bg1,
    const float* __restrict__ W0_2, const float* __restrict__ W1_2, const float* __restrict__ b_2,
    const float* __restrict__ Wg2,  const float* __restrict__ bg2,
    const float* __restrict__ W0_3, const float* __restrict__ b_3,
    const float* __restrict__ Wg3,  const float* __restrict__ bg3,
    float* __restrict__ acc, int N)
{
    int d = blockIdx.x * blockDim.x + threadIdx.x;
    float sf[5] = {0.f, 0.f, 0.f, 0.f, 0.f};

    if (d < N) {
        float cnt = sum4[4*d+3];
        if (cnt > 0.0f) {
            float invc = 1.0f / cnt;
            float m[3] = { sum4[4*d+0]*invc, sum4[4*d+1]*invc, sum4[4*d+2]*invc };

            // ---- layer 1 ----
            float s1[5], v1[5][3];
            #pragma unroll
            for (int i = 0; i < 5; ++i) {
                s1[i] = W0_1[i] + b_1[i];
                #pragma unroll
                for (int c = 0; c < 3; ++c) v1[i][c] = W1_1[i*3+c] * m[c];
            }
            // ---- gate 1 ----
            float g1[10];
            #pragma unroll
            for (int j = 0; j < 10; ++j) {
                float t = bg1[j];
                #pragma unroll
                for (int i = 0; i < 5; ++i) t += Wg1[j*5+i] * s1[i];
                g1[j] = gelu_exact(t);
            }
            #pragma unroll
            for (int i = 0; i < 5; ++i) {
                s1[i] *= g1[i];
                #pragma unroll
                for (int c = 0; c < 3; ++c) v1[i][c] *= g1[5+i];
            }

            // ---- layer 2 ----
            float dot1[5];
            #pragma unroll
            for (int i = 0; i < 5; ++i)
                dot1[i] = (v1[i][0]*m[0] + v1[i][1]*m[1] + v1[i][2]*m[2]) * INV_SQRT3F;
            float s2[5];
            #pragma unroll
            for (int o = 0; o < 5; ++o) {
                float t = b_2[o];
                #pragma unroll
                for (int i = 0; i < 5; ++i) t += W0_2[o*10+i] * s1[i];
                #pragma unroll
                for (int i = 0; i < 5; ++i) t += W0_2[o*10+5+i] * dot1[i];
                s2[o] = t;
            }
            float v2[5][3];
            #pragma unroll
            for (int o = 0; o < 5; ++o) {
                #pragma unroll
                for (int c = 0; c < 3; ++c) {
                    float t = 0.f;
                    #pragma unroll
                    for (int i = 0; i < 5; ++i) {
                        t += W1_2[(o*10+i)*3+c]   * (s1[i] * m[c]);
                        t += W1_2[(o*10+5+i)*3+c] * v1[i][c];
                    }
                    v2[o][c] = t;
                }
            }
            // ---- gate 2 ----
            float g2[10];
            #pragma unroll
            for (int j = 0; j < 10; ++j) {
                float t = bg2[j];
                #pragma unroll
                for (int i = 0; i < 5; ++i) t += Wg2[j*5+i] * s2[i];
                g2[j] = gelu_exact(t);
            }
            #pragma unroll
            for (int i = 0; i < 5; ++i) {
                s2[i] *= g2[i];
                #pragma unroll
                for (int c = 0; c < 3; ++c) v2[i][c] *= g2[5+i];
            }

            // ---- layer 3 ----
            float dot2[5];
            #pragma unroll
            for (int i = 0; i < 5; ++i)
                dot2[i] = (v2[i][0]*m[0] + v2[i][1]*m[1] + v2[i][2]*m[2]) * INV_SQRT3F;
            float s3[5];
            #pragma unroll
            for (int o = 0; o < 5; ++o) {
                float t = b_3[o];
                #pragma unroll
                for (int i = 0; i < 5; ++i) t += W0_3[o*10+i] * s2[i];
                #pragma unroll
                for (int i = 0; i < 5; ++i) t += W0_3[o*10+5+i] * dot2[i];
                s3[o] = t;
            }
            // ---- gate 3 (only first 5 of g needed) ----
            #pragma unroll
            for (int i = 0; i < 5; ++i) {
                float t = bg3[i];
                #pragma unroll
                for (int j = 0; j < 5; ++j) t += Wg3[i*5+j] * s3[j];
                sf[i] = gelu_exact(t) * s3[i];
            }
        }
    }

    // wave-64 shuffle reduction, one atomicAdd per wave per channel
    #pragma unroll
    for (int k = 0; k < 5; ++k) {
        float v = sf[k];
        for (int off = 32; off > 0; off >>= 1) v += __shfl_down(v, off);
        if ((threadIdx.x & 63) == 0) atomicAdd(&acc[k], v);
    }
}

// Kernel C: pooled mean -> logits -> softmax (10 outputs)
__global__ void finalize_kernel(
    const float* __restrict__ acc,
    const float* __restrict__ Wout, const float* __restrict__ bout,
    float* __restrict__ out, float invN)
{
    if (threadIdx.x == 0) {
        float pooled[5];
        #pragma unroll
        for (int i = 0; i < 5; ++i) pooled[i] = acc[i] * invN;
        float lg[10], mx = -1e30f;
        #pragma unroll
        for (int j = 0; j < 10; ++j) {
            float t = bout[j];
            #pragma unroll
            for (int i = 0; i < 5; ++i) t += Wout[j*5+i] * pooled[i];
            lg[j] = t;
            mx = fmaxf(mx, t);
        }
        float se = 0.f;
        #pragma unroll
        for (int j = 0; j < 10; ++j) { lg[j] = expf(lg[j] - mx); se += lg[j]; }
        float inv = 1.0f / se;
        #pragma unroll
        for (int j = 0; j < 10; ++j) out[j] = lg[j] * inv;
    }
}

extern "C" void kernel_launch(void* const* d_in, const int* in_sizes, int n_in,
                              void* d_out, int out_size, void* d_ws, size_t ws_size,
                              hipStream_t stream) {
    const float* pos  = (const float*)d_in[0];
    const int*   esrc = (const int*)d_in[1];
    const int*   edst = (const int*)d_in[2];
    const float* W0_1 = (const float*)d_in[3];
    const float* W1_1 = (const float*)d_in[4];
    const float* b_1  = (const float*)d_in[5];
    const float* Wg1  = (const float*)d_in[6];
    const float* bg1  = (const float*)d_in[7];
    const float* W0_2 = (const float*)d_in[8];
    const float* W1_2 = (const float*)d_in[9];
    const float* b_2  = (const float*)d_in[10];
    const float* Wg2  = (const float*)d_in[11];
    const float* bg2  = (const float*)d_in[12];
    const float* W0_3 = (const float*)d_in[13];
    const float* b_3  = (const float*)d_in[14];
    const float* Wg3  = (const float*)d_in[15];
    const float* bg3  = (const float*)d_in[16];
    const float* Wout = (const float*)d_in[17];
    const float* bout = (const float*)d_in[18];

    const int N = in_sizes[0] / 3;
    const int E = in_sizes[1];

    float* sum4 = (float*)d_ws;            // [N*4] sumSh.xyz + count
    float* acc  = sum4 + (size_t)4 * N;    // [5] pooled accumulator (+pad)

    // zero accumulators (graph-capture-safe async memset)
    hipMemsetAsync(d_ws, 0, ((size_t)4 * N + 8) * sizeof(float), stream);

    int eblocks = (E + 255) / 256;
    if (eblocks > 4096) eblocks = 4096;
    edge_kernel<<<eblocks, 256, 0, stream>>>(pos, esrc, edst, sum4, E);

    int nblocks = (N + 255) / 256;
    node_kernel<<<nblocks, 256, 0, stream>>>(sum4,
        W0_1, W1_1, b_1, Wg1, bg1,
        W0_2, W1_2, b_2, Wg2, bg2,
        W0_3, b_3, Wg3, bg3,
        acc, N);

    finalize_kernel<<<1, 64, 0, stream>>>(acc, Wout, bout, (float*)d_out, 1.0f / (float)N);
}

// Round 2
// 407.678 us; speedup vs baseline: 1.8629x; 1.8629x over previous
//
#include <hip/hip_runtime.h>
#include <math.h>

#define SQRT3F 1.7320508075688772f
#define INV_SQRT3F 0.57735026918962576f
#define FXS 2097152.0f     // 2^21 fixed-point scale
#define FXB 4194304u       // bias 2^22 > sqrt(3)*FXS, keeps each addend positive
typedef unsigned long long u64;
typedef unsigned int u32;

__device__ __forceinline__ float gelu_exact(float x) {
    return 0.5f * x * (1.0f + erff(x * 0.70710678118654752f));
}

__device__ __forceinline__ u32 fx(float v) {
    return (u32)__float2int_rn(v * FXS) + FXB;
}

// Kernel A: per-edge SH accumulation, 2 packed u64 atomics per edge.
// WG=true: per-XCD replica + workgroup-scope atomics (execute in XCD-local L2).
template<bool WG>
__global__ __launch_bounds__(256) void edge_kernel(
    const float* __restrict__ pos,
    const int* __restrict__ src,
    const int* __restrict__ dst,
    u64* __restrict__ reps, size_t repStride, int E)
{
    u64* rep = reps;
    if (WG) {
        u32 xcc;
        asm("s_getreg_b32 %0, hwreg(HW_REG_XCC_ID)" : "=s"(xcc));
        rep = reps + (size_t)(xcc & 7u) * repStride;
    }
    int stride = gridDim.x * blockDim.x;
    for (int i = blockIdx.x * blockDim.x + threadIdx.x; i < E; i += stride) {
        int s = src[i], d = dst[i];
        float rx = pos[3*d+0] - pos[3*s+0];
        float ry = pos[3*d+1] - pos[3*s+1];
        float rz = pos[3*d+2] - pos[3*s+2];
        float r = sqrtf(rx*rx + ry*ry + rz*rz);
        float inv = SQRT3F / fmaxf(r, 1e-9f);
        // word0: low = x, high = y ; word1: low = z, high = count(+1)
        u64 w0 = ((u64)fx(ry*inv) << 32) | (u64)fx(rx*inv);
        u64 w1 = (1ull << 32)            | (u64)fx(rz*inv);
        u64* p = rep + 2u * (size_t)(u32)d;
        if (WG) {
            __hip_atomic_fetch_add(p,     w0, __ATOMIC_RELAXED, __HIP_MEMORY_SCOPE_WORKGROUP);
            __hip_atomic_fetch_add(p + 1, w1, __ATOMIC_RELAXED, __HIP_MEMORY_SCOPE_WORKGROUP);
        } else {
            __hip_atomic_fetch_add(p,     w0, __ATOMIC_RELAXED, __HIP_MEMORY_SCOPE_AGENT);
            __hip_atomic_fetch_add(p + 1, w1, __ATOMIC_RELAXED, __HIP_MEMORY_SCOPE_AGENT);
        }
    }
}

// Kernel B: decode replicas -> meanSh, per-node closed-form 3-layer net, reduce to acc[5]
__global__ __launch_bounds__(256) void node_kernel(
    const u64* __restrict__ reps, size_t repStride, int R,
    const float* __restrict__ W0_1, const float* __restrict__ W1_1, const float* __restrict__ b_1,
    const float* __restrict__ Wg1,  const float* __restrict__ bg1,
    const float* __restrict__ W0_2, const float* __restrict__ W1_2, const float* __restrict__ b_2,
    const float* __restrict__ Wg2,  const float* __restrict__ bg2,
    const float* __restrict__ W0_3, const float* __restrict__ b_3,
    const float* __restrict__ Wg3,  const float* __restrict__ bg3,
    float* __restrict__ acc, int N)
{
    int d = blockIdx.x * blockDim.x + threadIdx.x;
    float sf[5] = {0.f, 0.f, 0.f, 0.f, 0.f};

    if (d < N) {
        u64 a = 0, b = 0;
        for (int r = 0; r < R; ++r) {
            a += reps[(size_t)r * repStride + 2u*(size_t)d];
            b += reps[(size_t)r * repStride + 2u*(size_t)d + 1];
        }
        u32 deg = (u32)(b >> 32);
        if (deg > 0) {
            long long lb = (long long)deg * (long long)FXB;
            float invdS = 1.0f / (FXS * (float)deg);
            float m[3];
            m[0] = (float)((long long)(u32)(a)       - lb) * invdS;
            m[1] = (float)((long long)(u32)(a >> 32) - lb) * invdS;
            m[2] = (float)((long long)(u32)(b)       - lb) * invdS;

            // ---- layer 1 ----
            float s1[5], v1[5][3];
            #pragma unroll
            for (int i = 0; i < 5; ++i) {
                s1[i] = W0_1[i] + b_1[i];
                #pragma unroll
                for (int c = 0; c < 3; ++c) v1[i][c] = W1_1[i*3+c] * m[c];
            }
            // ---- gate 1 ----
            float g1[10];
            #pragma unroll
            for (int j = 0; j < 10; ++j) {
                float t = bg1[j];
                #pragma unroll
                for (int i = 0; i < 5; ++i) t += Wg1[j*5+i] * s1[i];
                g1[j] = gelu_exact(t);
            }
            #pragma unroll
            for (int i = 0; i < 5; ++i) {
                s1[i] *= g1[i];
                #pragma unroll
                for (int c = 0; c < 3; ++c) v1[i][c] *= g1[5+i];
            }

            // ---- layer 2 ----
            float dot1[5];
            #pragma unroll
            for (int i = 0; i < 5; ++i)
                dot1[i] = (v1[i][0]*m[0] + v1[i][1]*m[1] + v1[i][2]*m[2]) * INV_SQRT3F;
            float s2[5];
            #pragma unroll
            for (int o = 0; o < 5; ++o) {
                float t = b_2[o];
                #pragma unroll
                for (int i = 0; i < 5; ++i) t += W0_2[o*10+i] * s1[i];
                #pragma unroll
                for (int i = 0; i < 5; ++i) t += W0_2[o*10+5+i] * dot1[i];
                s2[o] = t;
            }
            float v2[5][3];
            #pragma unroll
            for (int o = 0; o < 5; ++o) {
                #pragma unroll
                for (int c = 0; c < 3; ++c) {
                    float t = 0.f;
                    #pragma unroll
                    for (int i = 0; i < 5; ++i) {
                        t += W1_2[(o*10+i)*3+c]   * (s1[i] * m[c]);
                        t += W1_2[(o*10+5+i)*3+c] * v1[i][c];
                    }
                    v2[o][c] = t;
                }
            }
            // ---- gate 2 ----
            float g2[10];
            #pragma unroll
            for (int j = 0; j < 10; ++j) {
                float t = bg2[j];
                #pragma unroll
                for (int i = 0; i < 5; ++i) t += Wg2[j*5+i] * s2[i];
                g2[j] = gelu_exact(t);
            }
            #pragma unroll
            for (int i = 0; i < 5; ++i) {
                s2[i] *= g2[i];
                #pragma unroll
                for (int c = 0; c < 3; ++c) v2[i][c] *= g2[5+i];
            }

            // ---- layer 3 ----
            float dot2[5];
            #pragma unroll
            for (int i = 0; i < 5; ++i)
                dot2[i] = (v2[i][0]*m[0] + v2[i][1]*m[1] + v2[i][2]*m[2]) * INV_SQRT3F;
            float s3[5];
            #pragma unroll
            for (int o = 0; o < 5; ++o) {
                float t = b_3[o];
                #pragma unroll
                for (int i = 0; i < 5; ++i) t += W0_3[o*10+i] * s2[i];
                #pragma unroll
                for (int i = 0; i < 5; ++i) t += W0_3[o*10+5+i] * dot2[i];
                s3[o] = t;
            }
            // ---- gate 3 ----
            #pragma unroll
            for (int i = 0; i < 5; ++i) {
                float t = bg3[i];
                #pragma unroll
                for (int j = 0; j < 5; ++j) t += Wg3[i*5+j] * s3[j];
                sf[i] = gelu_exact(t) * s3[i];
            }
        }
    }

    // wave-64 shuffle reduction, one atomicAdd per wave per channel
    #pragma unroll
    for (int k = 0; k < 5; ++k) {
        float v = sf[k];
        for (int off = 32; off > 0; off >>= 1) v += __shfl_down(v, off);
        if ((threadIdx.x & 63) == 0) atomicAdd(&acc[k], v);
    }
}

// Kernel C: pooled mean -> logits -> softmax (10 outputs)
__global__ void finalize_kernel(
    const float* __restrict__ acc,
    const float* __restrict__ Wout, const float* __restrict__ bout,
    float* __restrict__ out, float invN)
{
    if (threadIdx.x == 0) {
        float pooled[5];
        #pragma unroll
        for (int i = 0; i < 5; ++i) pooled[i] = acc[i] * invN;
        float lg[10], mx = -1e30f;
        #pragma unroll
        for (int j = 0; j < 10; ++j) {
            float t = bout[j];
            #pragma unroll
            for (int i = 0; i < 5; ++i) t += Wout[j*5+i] * pooled[i];
            lg[j] = t;
            mx = fmaxf(mx, t);
        }
        float se = 0.f;
        #pragma unroll
        for (int j = 0; j < 10; ++j) { lg[j] = expf(lg[j] - mx); se += lg[j]; }
        float inv = 1.0f / se;
        #pragma unroll
        for (int j = 0; j < 10; ++j) out[j] = lg[j] * inv;
    }
}

extern "C" void kernel_launch(void* const* d_in, const int* in_sizes, int n_in,
                              void* d_out, int out_size, void* d_ws, size_t ws_size,
                              hipStream_t stream) {
    const float* pos  = (const float*)d_in[0];
    const int*   esrc = (const int*)d_in[1];
    const int*   edst = (const int*)d_in[2];
    const float* W0_1 = (const float*)d_in[3];
    const float* W1_1 = (const float*)d_in[4];
    const float* b_1  = (const float*)d_in[5];
    const float* Wg1  = (const float*)d_in[6];
    const float* bg1  = (const float*)d_in[7];
    const float* W0_2 = (const float*)d_in[8];
    const float* W1_2 = (const float*)d_in[9];
    const float* b_2  = (const float*)d_in[10];
    const float* Wg2  = (const float*)d_in[11];
    const float* bg2  = (const float*)d_in[12];
    const float* W0_3 = (const float*)d_in[13];
    const float* b_3  = (const float*)d_in[14];
    const float* Wg3  = (const float*)d_in[15];
    const float* bg3  = (const float*)d_in[16];
    const float* Wout = (const float*)d_in[17];
    const float* bout = (const float*)d_in[18];

    const int N = in_sizes[0] / 3;
    const int E = in_sizes[1];

    // layout: [acc: 16 floats pad to 64B][replicas: R * N * 2 u64]
    float* acc   = (float*)d_ws;
    u64*   reps  = (u64*)((char*)d_ws + 64);
    size_t repStride = (size_t)2 * N;   // u64 elements per replica

    size_t need8 = 64 + (size_t)8 * repStride * sizeof(u64);
    int R = (ws_size >= need8) ? 8 : 1;
    size_t zbytes = 64 + (size_t)R * repStride * sizeof(u64);

    hipMemsetAsync(d_ws, 0, zbytes, stream);

    int eblocks = (E + 255) / 256;
    if (eblocks > 4096) eblocks = 4096;
    if (R == 8) {
        edge_kernel<true ><<<eblocks, 256, 0, stream>>>(pos, esrc, edst, reps, repStride, E);
    } else {
        edge_kernel<false><<<eblocks, 256, 0, stream>>>(pos, esrc, edst, reps, repStride, E);
    }

    int nblocks = (N + 255) / 256;
    node_kernel<<<nblocks, 256, 0, stream>>>(reps, repStride, R,
        W0_1, W1_1, b_1, Wg1, bg1,
        W0_2, W1_2, b_2, Wg2, bg2,
        W0_3, b_3, Wg3, bg3,
        acc, N);

    finalize_kernel<<<1, 64, 0, stream>>>(acc, Wout, bout, (float*)d_out, 1.0f / (float)N);
}

// Round 3
// 172.179 us; speedup vs baseline: 4.4109x; 2.3677x over previous
//
#include <hip/hip_runtime.h>
#include <math.h>

#define SQRT3F 1.7320508075688772f
#define INV_SQRT3F 0.57735026918962576f
typedef unsigned long long u64;
typedef unsigned int u32;

// packing: [x:19][y:19][z:19][count:7], per-addend scale 1024, bias 2048
#define PK_SCALE 1024.0f
#define PK_BIAS  2048u
#define PK_MASK  0x7FFFFull

__device__ __forceinline__ float gelu_exact(float x) {
    return 0.5f * x * (1.0f + erff(x * 0.70710678118654752f));
}

// Kernel A: per-edge SH accumulation, ONE packed u64 atomic per edge.
template<bool WG>
__global__ __launch_bounds__(256) void edge_kernel(
    const float* __restrict__ pos,
    const int* __restrict__ src,
    const int* __restrict__ dst,
    u64* __restrict__ reps, size_t repStride, int E)
{
    u64* rep = reps;
    if (WG) {
        u32 xcc;
        asm("s_getreg_b32 %0, hwreg(HW_REG_XCC_ID)" : "=s"(xcc));
        rep = reps + (size_t)(xcc & 7u) * repStride;
    }
    int stride = gridDim.x * blockDim.x;
    for (int i = blockIdx.x * blockDim.x + threadIdx.x; i < E; i += stride) {
        int s = src[i], d = dst[i];
        float rx = pos[3*d+0] - pos[3*s+0];
        float ry = pos[3*d+1] - pos[3*s+1];
        float rz = pos[3*d+2] - pos[3*s+2];
        float r = sqrtf(rx*rx + ry*ry + rz*rz);
        float inv = (SQRT3F * PK_SCALE) / fmaxf(r, 1e-9f);
        u32 ax = (u32)__float2int_rn(rx * inv) + PK_BIAS;
        u32 ay = (u32)__float2int_rn(ry * inv) + PK_BIAS;
        u32 az = (u32)__float2int_rn(rz * inv) + PK_BIAS;
        u64 w = (u64)ax | ((u64)ay << 19) | ((u64)az << 38) | (1ull << 57);
        if (WG) {
            __hip_atomic_fetch_add(rep + (u32)d, w, __ATOMIC_RELAXED, __HIP_MEMORY_SCOPE_WORKGROUP);
        } else {
            __hip_atomic_fetch_add(rep + (u32)d, w, __ATOMIC_RELAXED, __HIP_MEMORY_SCOPE_AGENT);
        }
    }
}

// Kernel B: decode replicas -> meanSh, closed-form 3-layer net, block partials (no atomics)
__global__ __launch_bounds__(256) void node_kernel(
    const u64* __restrict__ reps, size_t repStride, int R,
    const float* __restrict__ W0_1, const float* __restrict__ W1_1, const float* __restrict__ b_1,
    const float* __restrict__ Wg1,  const float* __restrict__ bg1,
    const float* __restrict__ W0_2, const float* __restrict__ W1_2, const float* __restrict__ b_2,
    const float* __restrict__ Wg2,  const float* __restrict__ bg2,
    const float* __restrict__ W0_3, const float* __restrict__ b_3,
    const float* __restrict__ Wg3,  const float* __restrict__ bg3,
    float* __restrict__ partials, int N)
{
    int d = blockIdx.x * blockDim.x + threadIdx.x;
    float sf[5] = {0.f, 0.f, 0.f, 0.f, 0.f};

    if (d < N) {
        u64 w = 0;
        for (int r = 0; r < R; ++r) w += reps[(size_t)r * repStride + (u32)d];
        u32 deg = (u32)(w >> 57);
        if (deg > 0) {
            long long bias = (long long)deg << 11;   // deg * 2048
            float invdS = 1.0f / (PK_SCALE * (float)deg);
            float m[3];
            m[0] = (float)((long long)( w        & PK_MASK) - bias) * invdS;
            m[1] = (float)((long long)((w >> 19) & PK_MASK) - bias) * invdS;
            m[2] = (float)((long long)((w >> 38) & PK_MASK) - bias) * invdS;

            // ---- layer 1 ----
            float s1[5], v1[5][3];
            #pragma unroll
            for (int i = 0; i < 5; ++i) {
                s1[i] = W0_1[i] + b_1[i];
                #pragma unroll
                for (int c = 0; c < 3; ++c) v1[i][c] = W1_1[i*3+c] * m[c];
            }
            // ---- gate 1 ----
            float g1[10];
            #pragma unroll
            for (int j = 0; j < 10; ++j) {
                float t = bg1[j];
                #pragma unroll
                for (int i = 0; i < 5; ++i) t += Wg1[j*5+i] * s1[i];
                g1[j] = gelu_exact(t);
            }
            #pragma unroll
            for (int i = 0; i < 5; ++i) {
                s1[i] *= g1[i];
                #pragma unroll
                for (int c = 0; c < 3; ++c) v1[i][c] *= g1[5+i];
            }

            // ---- layer 2 ----
            float dot1[5];
            #pragma unroll
            for (int i = 0; i < 5; ++i)
                dot1[i] = (v1[i][0]*m[0] + v1[i][1]*m[1] + v1[i][2]*m[2]) * INV_SQRT3F;
            float s2[5];
            #pragma unroll
            for (int o = 0; o < 5; ++o) {
                float t = b_2[o];
                #pragma unroll
                for (int i = 0; i < 5; ++i) t += W0_2[o*10+i] * s1[i];
                #pragma unroll
                for (int i = 0; i < 5; ++i) t += W0_2[o*10+5+i] * dot1[i];
                s2[o] = t;
            }
            float v2[5][3];
            #pragma unroll
            for (int o = 0; o < 5; ++o) {
                #pragma unroll
                for (int c = 0; c < 3; ++c) {
                    float t = 0.f;
                    #pragma unroll
                    for (int i = 0; i < 5; ++i) {
                        t += W1_2[(o*10+i)*3+c]   * (s1[i] * m[c]);
                        t += W1_2[(o*10+5+i)*3+c] * v1[i][c];
                    }
                    v2[o][c] = t;
                }
            }
            // ---- gate 2 ----
            float g2[10];
            #pragma unroll
            for (int j = 0; j < 10; ++j) {
                float t = bg2[j];
                #pragma unroll
                for (int i = 0; i < 5; ++i) t += Wg2[j*5+i] * s2[i];
                g2[j] = gelu_exact(t);
            }
            #pragma unroll
            for (int i = 0; i < 5; ++i) {
                s2[i] *= g2[i];
                #pragma unroll
                for (int c = 0; c < 3; ++c) v2[i][c] *= g2[5+i];
            }

            // ---- layer 3 ----
            float dot2[5];
            #pragma unroll
            for (int i = 0; i < 5; ++i)
                dot2[i] = (v2[i][0]*m[0] + v2[i][1]*m[1] + v2[i][2]*m[2]) * INV_SQRT3F;
            float s3[5];
            #pragma unroll
            for (int o = 0; o < 5; ++o) {
                float t = b_3[o];
                #pragma unroll
                for (int i = 0; i < 5; ++i) t += W0_3[o*10+i] * s2[i];
                #pragma unroll
                for (int i = 0; i < 5; ++i) t += W0_3[o*10+5+i] * dot2[i];
                s3[o] = t;
            }
            // ---- gate 3 ----
            #pragma unroll
            for (int i = 0; i < 5; ++i) {
                float t = bg3[i];
                #pragma unroll
                for (int j = 0; j < 5; ++j) t += Wg3[i*5+j] * s3[j];
                sf[i] = gelu_exact(t) * s3[i];
            }
        }
    }

    // wave shuffle reduce -> LDS -> one store of 5 partials per block (NO atomics)
    #pragma unroll
    for (int k = 0; k < 5; ++k) {
        float v = sf[k];
        for (int off = 32; off > 0; off >>= 1) v += __shfl_down(v, off);
        sf[k] = v;
    }
    __shared__ float lred[4][5];
    int wid = threadIdx.x >> 6, lane = threadIdx.x & 63;
    if (lane == 0) {
        #pragma unroll
        for (int k = 0; k < 5; ++k) lred[wid][k] = sf[k];
    }
    __syncthreads();
    if (threadIdx.x == 0) {
        #pragma unroll
        for (int k = 0; k < 5; ++k)
            partials[blockIdx.x * 5 + k] = lred[0][k] + lred[1][k] + lred[2][k] + lred[3][k];
    }
}

// Kernel C: reduce block partials -> pooled mean -> logits -> softmax
__global__ __launch_bounds__(256) void finalize_kernel(
    const float* __restrict__ partials, int nb,
    const float* __restrict__ Wout, const float* __restrict__ bout,
    float* __restrict__ out, float invN)
{
    float s[5] = {0.f, 0.f, 0.f, 0.f, 0.f};
    for (int b = threadIdx.x; b < nb; b += 256) {
        #pragma unroll
        for (int k = 0; k < 5; ++k) s[k] += partials[b * 5 + k];
    }
    #pragma unroll
    for (int k = 0; k < 5; ++k) {
        float v = s[k];
        for (int off = 32; off > 0; off >>= 1) v += __shfl_down(v, off);
        s[k] = v;
    }
    __shared__ float lred[4][5];
    int wid = threadIdx.x >> 6, lane = threadIdx.x & 63;
    if (lane == 0) {
        #pragma unroll
        for (int k = 0; k < 5; ++k) lred[wid][k] = s[k];
    }
    __syncthreads();
    if (threadIdx.x == 0) {
        float pooled[5];
        #pragma unroll
        for (int i = 0; i < 5; ++i)
            pooled[i] = (lred[0][i] + lred[1][i] + lred[2][i] + lred[3][i]) * invN;
        float lg[10], mx = -1e30f;
        #pragma unroll
        for (int j = 0; j < 10; ++j) {
            float t = bout[j];
            #pragma unroll
            for (int i = 0; i < 5; ++i) t += Wout[j*5+i] * pooled[i];
            lg[j] = t;
            mx = fmaxf(mx, t);
        }
        float se = 0.f;
        #pragma unroll
        for (int j = 0; j < 10; ++j) { lg[j] = expf(lg[j] - mx); se += lg[j]; }
        float inv = 1.0f / se;
        #pragma unroll
        for (int j = 0; j < 10; ++j) out[j] = lg[j] * inv;
    }
}

extern "C" void kernel_launch(void* const* d_in, const int* in_sizes, int n_in,
                              void* d_out, int out_size, void* d_ws, size_t ws_size,
                              hipStream_t stream) {
    const float* pos  = (const float*)d_in[0];
    const int*   esrc = (const int*)d_in[1];
    const int*   edst = (const int*)d_in[2];
    const float* W0_1 = (const float*)d_in[3];
    const float* W1_1 = (const float*)d_in[4];
    const float* b_1  = (const float*)d_in[5];
    const float* Wg1  = (const float*)d_in[6];
    const float* bg1  = (const float*)d_in[7];
    const float* W0_2 = (const float*)d_in[8];
    const float* W1_2 = (const float*)d_in[9];
    const float* b_2  = (const float*)d_in[10];
    const float* Wg2  = (const float*)d_in[11];
    const float* bg2  = (const float*)d_in[12];
    const float* W0_3 = (const float*)d_in[13];
    const float* b_3  = (const float*)d_in[14];
    const float* Wg3  = (const float*)d_in[15];
    const float* bg3  = (const float*)d_in[16];
    const float* Wout = (const float*)d_in[17];
    const float* bout = (const float*)d_in[18];

    const int N = in_sizes[0] / 3;
    const int E = in_sizes[1];

    // ws layout: [partials: 16KB][replicas: R * N u64]
    float* partials = (float*)d_ws;
    u64*   reps     = (u64*)((char*)d_ws + 16384);
    size_t repStride = (size_t)N;   // u64 elements per replica

    size_t need8 = 16384 + (size_t)8 * repStride * sizeof(u64);
    int R = (ws_size >= need8) ? 8 : 1;

    // zero only the replica region (partials are written unconditionally)
    hipMemsetAsync(reps, 0, (size_t)R * repStride * sizeof(u64), stream);

    int eblocks = (E + 255) / 256;
    if (eblocks > 4096) eblocks = 4096;
    if (R == 8) {
        edge_kernel<true ><<<eblocks, 256, 0, stream>>>(pos, esrc, edst, reps, repStride, E);
    } else {
        edge_kernel<false><<<eblocks, 256, 0, stream>>>(pos, esrc, edst, reps, repStride, E);
    }

    int nblocks = (N + 255) / 256;
    node_kernel<<<nblocks, 256, 0, stream>>>(reps, repStride, R,
        W0_1, W1_1, b_1, Wg1, bg1,
        W0_2, W1_2, b_2, Wg2, bg2,
        W0_3, b_3, Wg3, bg3,
        partials, N);

    finalize_kernel<<<1, 256, 0, stream>>>(partials, nblocks, Wout, bout,
                                           (float*)d_out, 1.0f / (float)N);
}